// Round 10
// baseline (88.860 us; speedup 1.0000x reference)
//
#include <hip/hip_runtime.h>

#define NBLK 128
#define BB   4
#define SS   4096
#define DD   1024
#define PLANE (BB * SS * DD)          // 16,777,216 floats per output plane
#define APPLY_WGS 1024
#define THREADS (APPLY_WGS * 256)     // 262,144 threads
#define NITER (PLANE / 4 / THREADS)   // 16 float4-chunks per thread

typedef float floatx4 __attribute__((ext_vector_type(4)));

// ---------------------------------------------------------------------------
// Kernel 1: Cayley transform. 128 independent 16x16 solves. 64-thread
// workgroups (1 wave) x 32 wgs — intra-wave barriers, 32 CUs busy.
// ---------------------------------------------------------------------------
__global__ __launch_bounds__(64) void cayley_kernel(
    const float* __restrict__ Ar, const float* __restrict__ Ai,
    float* __restrict__ Ur, float* __restrict__ Ui) {
  __shared__ float piv[4][33];
  const int s = threadIdx.x >> 4;        // solve slot (0..3)
  const int r = threadIdx.x & 15;        // my row of the 16x32 augmented mat
  const int n = blockIdx.x * 4 + s;      // block index 0..127
  const float* arb = Ar + n * 64;
  const float* aib = Ai + n * 64;

  float row[32];
  if (r < 8) {
    #pragma unroll
    for (int c = 0; c < 8; ++c) {
      float sk = 0.5f * (arb[r * 8 + c] - arb[c * 8 + r]);
      float sy = 0.5f * (aib[r * 8 + c] + aib[c * 8 + r]);
      float d  = (c == r) ? 1.0f : 0.0f;
      row[c]      = d + sk;
      row[8 + c]  = -sy;
      row[16 + c] = d - sk;
      row[24 + c] = sy;
    }
  } else {
    const int rr = r - 8;
    #pragma unroll
    for (int c = 0; c < 8; ++c) {
      float sk = 0.5f * (arb[rr * 8 + c] - arb[c * 8 + rr]);
      float sy = 0.5f * (aib[rr * 8 + c] + aib[c * 8 + rr]);
      float d  = (c == rr) ? 1.0f : 0.0f;
      row[c]      = sy;
      row[8 + c]  = d + sk;
      row[16 + c] = -sy;
      row[24 + c] = d - sk;
    }
  }

  #pragma unroll
  for (int k = 0; k < 16; ++k) {
    if (r == k) {
      float inv = 1.0f / row[k];
      #pragma unroll
      for (int j = 0; j < 32; ++j) { row[j] *= inv; piv[s][j] = row[j]; }
    }
    __syncthreads();
    if (r != k) {
      float f = row[k];
      #pragma unroll
      for (int j = 0; j < 32; ++j) row[j] = fmaf(-f, piv[s][j], row[j]);
    }
    __syncthreads();
  }

  if (r < 8) {
    #pragma unroll
    for (int c = 0; c < 8; ++c) Ur[n * 64 + r * 8 + c] = row[16 + c];
  } else {
    #pragma unroll
    for (int c = 0; c < 8; ++c) Ui[n * 64 + (r - 8) * 8 + c] = row[16 + c];
  }
}

// ---------------------------------------------------------------------------
// Kernel 2 (R10): barrier-free wave-private global_load_lds pipeline.
//  - Each wave stages chunk c (its 64 lanes' float4 of xr AND xi = 2 KB)
//    into private LDS buffers (DEPTH=4, 8 KB/wave, 32 KB/wg) via
//    __builtin_amdgcn_global_load_lds width=16. No dest VGPRs -> load
//    latency decoupled from register pressure; 3 chunks prefetched ahead.
//  - Compute reads own + partner (lane^1, SAME wave -> no barrier ever)
//    via ds_read_b128: kills R8's duplicate global reads (2x VMEM rate).
//  - Hand-counted s_waitcnt vmcnt(N): per-iter VMEM ledger is exactly
//    {2 staging loads + 2 asm stores}; chunk k's loads are safe when the
//    12 newest ops may remain (steady state). Prologue 6/8/10, tail
//    10/8/6 (stores fill the queue). NEVER vmcnt(0) mid-loop.
//  - sched_barrier(0) after each wait (rule: hipcc may hoist past asm
//    waitcnt). Stores: sc0 sc1 nt as R9. Final vmcnt(0) drain.
// ---------------------------------------------------------------------------
__device__ __forceinline__ void stage_chunk(const float4* pxr, const float4* pxi,
                                            float* slot, int idx) {
  __builtin_amdgcn_global_load_lds(
      (const __attribute__((address_space(1))) void*)(pxr + idx),
      (__attribute__((address_space(3))) void*)slot, 16, 0, 0);
  __builtin_amdgcn_global_load_lds(
      (const __attribute__((address_space(1))) void*)(pxi + idx),
      (__attribute__((address_space(3))) void*)(slot + 256), 16, 0, 0);
}

template<int K, int W>
__device__ __forceinline__ void body(const float4* pxr, const float4* pxi,
                                     floatx4* qor, floatx4* qoi,
                                     float (*ldsw)[2][256],
                                     int lane, int G,
                                     const float (&u)[4][8], const float (&v)[4][8]) {
  if constexpr (K + 3 < NITER) {
    stage_chunk(pxr, pxi, &ldsw[(K + 3) & 3][0][0], (K + 3) * THREADS + G);
  }
  asm volatile("s_waitcnt vmcnt(%c0)" :: "i"(W) : "memory");
  __builtin_amdgcn_sched_barrier(0);

  const float* s0 = &ldsw[K & 3][0][0];
  float4 a  = *(const float4*)(s0 + lane * 4);          // own xr
  float4 ap = *(const float4*)(s0 + (lane ^ 1) * 4);    // partner xr
  float4 b  = *(const float4*)(s0 + 256 + lane * 4);    // own xi
  float4 bp = *(const float4*)(s0 + 256 + (lane ^ 1) * 4);

  float oxr[4] = {a.x, a.y, a.z, a.w};
  float oxi[4] = {b.x, b.y, b.z, b.w};
  float wxr[4] = {ap.x, ap.y, ap.z, ap.w};
  float wxi[4] = {bp.x, bp.y, bp.z, bp.w};

  floatx4 sr, si;
  #pragma unroll
  for (int j = 0; j < 4; ++j) {
    float r0 = u[j][0] * oxr[0];
    float i0 = u[j][0] * oxi[0];
    #pragma unroll
    for (int c = 1; c < 4; ++c) {
      r0 = fmaf(u[j][c], oxr[c], r0);
      i0 = fmaf(u[j][c], oxi[c], i0);
    }
    #pragma unroll
    for (int c = 0; c < 4; ++c) {
      r0 = fmaf(u[j][4 + c], wxr[c], r0);
      i0 = fmaf(u[j][4 + c], wxi[c], i0);
    }
    #pragma unroll
    for (int c = 0; c < 4; ++c) {
      r0 = fmaf(-v[j][c], oxi[c], r0);
      i0 = fmaf(v[j][c], oxr[c], i0);
    }
    #pragma unroll
    for (int c = 0; c < 4; ++c) {
      r0 = fmaf(-v[j][4 + c], wxi[c], r0);
      i0 = fmaf(v[j][4 + c], wxr[c], i0);
    }
    sr[j] = r0;
    si[j] = i0;
  }

  const int idx = K * THREADS + G;
  asm volatile("global_store_dwordx4 %0, %1, off sc0 sc1 nt"
               :: "v"(qor + idx), "v"(sr) : "memory");
  asm volatile("global_store_dwordx4 %0, %1, off sc0 sc1 nt"
               :: "v"(qoi + idx), "v"(si) : "memory");
}

__global__ __launch_bounds__(256, 4) void apply_kernel(
    const float* __restrict__ xr, const float* __restrict__ xi,
    const float* __restrict__ Urg, const float* __restrict__ Uig,
    float* __restrict__ out) {
  const int tid  = threadIdx.x;
  const int wid  = tid >> 6;             // wave id in wg (0..3)
  const int lane = tid & 63;
  const int G = blockIdx.x * 256 + tid;  // thread linear id
  const int p = G & 255;
  const int n = p >> 1;                  // block index, constant per thread
  const int h = p & 1;                   // which half of the block I own

  __shared__ float lds[4][4][2][256];    // [wave][depth][plane][64 lanes x 4f]

  // U rows o = h*4+j, columns permuted: [0..3]=own half, [4..7]=partner half.
  float u[4][8], v[4][8];
  #pragma unroll
  for (int j = 0; j < 4; ++j) {
    const float* urow = Urg + n * 64 + (h * 4 + j) * 8;
    const float* vrow = Uig + n * 64 + (h * 4 + j) * 8;
    float4 uo = *(const float4*)(urow + h * 4);
    float4 up = *(const float4*)(urow + (h ^ 1) * 4);
    float4 vo = *(const float4*)(vrow + h * 4);
    float4 vp = *(const float4*)(vrow + (h ^ 1) * 4);
    u[j][0] = uo.x; u[j][1] = uo.y; u[j][2] = uo.z; u[j][3] = uo.w;
    u[j][4] = up.x; u[j][5] = up.y; u[j][6] = up.z; u[j][7] = up.w;
    v[j][0] = vo.x; v[j][1] = vo.y; v[j][2] = vo.z; v[j][3] = vo.w;
    v[j][4] = vp.x; v[j][5] = vp.y; v[j][6] = vp.z; v[j][7] = vp.w;
  }
  // Pin U in registers (R1 failure mode: compiler sinks U loads into loop).
  #pragma unroll
  for (int j = 0; j < 4; ++j)
    #pragma unroll
    for (int c = 0; c < 8; ++c)
      asm volatile("" : "+v"(u[j][c]), "+v"(v[j][c]));

  const float4* pxr = (const float4*)xr;
  const float4* pxi = (const float4*)xi;
  floatx4* qor = (floatx4*)out;
  floatx4* qoi = (floatx4*)(out + PLANE);

  float (*ldsw)[2][256] = lds[wid];      // this wave's private buffers

  // Prologue: stage chunks 0,1,2 (6 loads in flight).
  stage_chunk(pxr, pxi, &ldsw[0][0][0], 0 * THREADS + G);
  stage_chunk(pxr, pxi, &ldsw[1][0][0], 1 * THREADS + G);
  stage_chunk(pxr, pxi, &ldsw[2][0][0], 2 * THREADS + G);

  // VMEM ledger (per wave, in order): see header comment. NITER == 16.
  body< 0,  6>(pxr, pxi, qor, qoi, ldsw, lane, G, u, v);
  body< 1,  8>(pxr, pxi, qor, qoi, ldsw, lane, G, u, v);
  body< 2, 10>(pxr, pxi, qor, qoi, ldsw, lane, G, u, v);
  body< 3, 12>(pxr, pxi, qor, qoi, ldsw, lane, G, u, v);
  body< 4, 12>(pxr, pxi, qor, qoi, ldsw, lane, G, u, v);
  body< 5, 12>(pxr, pxi, qor, qoi, ldsw, lane, G, u, v);
  body< 6, 12>(pxr, pxi, qor, qoi, ldsw, lane, G, u, v);
  body< 7, 12>(pxr, pxi, qor, qoi, ldsw, lane, G, u, v);
  body< 8, 12>(pxr, pxi, qor, qoi, ldsw, lane, G, u, v);
  body< 9, 12>(pxr, pxi, qor, qoi, ldsw, lane, G, u, v);
  body<10, 12>(pxr, pxi, qor, qoi, ldsw, lane, G, u, v);
  body<11, 12>(pxr, pxi, qor, qoi, ldsw, lane, G, u, v);
  body<12, 12>(pxr, pxi, qor, qoi, ldsw, lane, G, u, v);
  body<13, 10>(pxr, pxi, qor, qoi, ldsw, lane, G, u, v);
  body<14,  8>(pxr, pxi, qor, qoi, ldsw, lane, G, u, v);
  body<15,  6>(pxr, pxi, qor, qoi, ldsw, lane, G, u, v);

  // Drain asm stores before wave exit (compiler can't see them).
  asm volatile("s_waitcnt vmcnt(0)" ::: "memory");
}

extern "C" void kernel_launch(void* const* d_in, const int* in_sizes, int n_in,
                              void* d_out, int out_size, void* d_ws, size_t ws_size,
                              hipStream_t stream) {
  const float* xr = (const float*)d_in[0];
  const float* xi = (const float*)d_in[1];
  const float* Ar = (const float*)d_in[2];
  const float* Ai = (const float*)d_in[3];
  float* out = (float*)d_out;

  float* Ur = (float*)d_ws;              // 128*64 floats = 32 KB
  float* Ui = Ur + NBLK * 64;            // next 32 KB

  cayley_kernel<<<32, 64, 0, stream>>>(Ar, Ai, Ur, Ui);
  apply_kernel<<<APPLY_WGS, 256, 0, stream>>>(xr, xi, Ur, Ui, out);
}

// Round 11
// 59.148 us; speedup vs baseline: 1.5023x; 1.5023x over previous
//
#include <hip/hip_runtime.h>

#define NBLK 128
#define BB   4
#define SS   4096
#define DD   1024
#define PLANE (BB * SS * DD)          // 16,777,216 floats per output plane
#define APPLY_WGS 1024
#define THREADS (APPLY_WGS * 256)     // 262,144 threads
#define NITER (PLANE / 4 / THREADS)   // 16 float4-tiles per thread

typedef float floatx4 __attribute__((ext_vector_type(4)));

// ---------------------------------------------------------------------------
// Kernel 1: Cayley transform. 128 independent 16x16 solves. 64-thread
// workgroups (1 wave) x 32 wgs — intra-wave barriers, 32 CUs busy.
// ---------------------------------------------------------------------------
__global__ __launch_bounds__(64) void cayley_kernel(
    const float* __restrict__ Ar, const float* __restrict__ Ai,
    float* __restrict__ Ur, float* __restrict__ Ui) {
  __shared__ float piv[4][33];
  const int s = threadIdx.x >> 4;        // solve slot (0..3)
  const int r = threadIdx.x & 15;        // my row of the 16x32 augmented mat
  const int n = blockIdx.x * 4 + s;      // block index 0..127
  const float* arb = Ar + n * 64;
  const float* aib = Ai + n * 64;

  float row[32];
  if (r < 8) {
    #pragma unroll
    for (int c = 0; c < 8; ++c) {
      float sk = 0.5f * (arb[r * 8 + c] - arb[c * 8 + r]);
      float sy = 0.5f * (aib[r * 8 + c] + aib[c * 8 + r]);
      float d  = (c == r) ? 1.0f : 0.0f;
      row[c]      = d + sk;
      row[8 + c]  = -sy;
      row[16 + c] = d - sk;
      row[24 + c] = sy;
    }
  } else {
    const int rr = r - 8;
    #pragma unroll
    for (int c = 0; c < 8; ++c) {
      float sk = 0.5f * (arb[rr * 8 + c] - arb[c * 8 + rr]);
      float sy = 0.5f * (aib[rr * 8 + c] + aib[c * 8 + rr]);
      float d  = (c == rr) ? 1.0f : 0.0f;
      row[c]      = sy;
      row[8 + c]  = d + sk;
      row[16 + c] = -sy;
      row[24 + c] = d - sk;
    }
  }

  #pragma unroll
  for (int k = 0; k < 16; ++k) {
    if (r == k) {
      float inv = 1.0f / row[k];
      #pragma unroll
      for (int j = 0; j < 32; ++j) { row[j] *= inv; piv[s][j] = row[j]; }
    }
    __syncthreads();
    if (r != k) {
      float f = row[k];
      #pragma unroll
      for (int j = 0; j < 32; ++j) row[j] = fmaf(-f, piv[s][j], row[j]);
    }
    __syncthreads();
  }

  if (r < 8) {
    #pragma unroll
    for (int c = 0; c < 8; ++c) Ur[n * 64 + r * 8 + c] = row[16 + c];
  } else {
    #pragma unroll
    for (int c = 0; c < 8; ++c) Ui[n * 64 + (r - 8) * 8 + c] = row[16 + c];
  }
}

// ---------------------------------------------------------------------------
// Kernel 2 (R11 = R9 + ILP unblock):
//  (a) store asms DROP the "memory" clobber. In R8-R10 every store was a
//      full compiler memory barrier, so iter k+1's loads could never hoist
//      above iter k's stores -> strictly serial load/wait/FMA/store chain.
//      volatile keeps stores ordered among themselves and before the final
//      volatile drain; x/out never alias (__restrict, disjoint buffers).
//  (b) FMA accumulation reordered: ALL own-half products (need only a,b ->
//      compiler emits vmcnt(2)) before ALL partner-half products (vmcnt(0)).
//      64 FMAs of real work now cover half of each iteration's load latency.
//  R10 lessons: global_load_lds bypasses MALL (FETCH 66->134MB) — never use
//  it here; never put system-scope stores ahead of loads in a counted-vmcnt
//  FIFO schedule.
// ---------------------------------------------------------------------------
__global__ __launch_bounds__(256, 4) void apply_kernel(
    const float* __restrict__ xr, const float* __restrict__ xi,
    const float* __restrict__ Urg, const float* __restrict__ Uig,
    float* __restrict__ out) {
  const int G = blockIdx.x * 256 + threadIdx.x;   // thread linear id
  const int p = G & 255;         // position within 256-float4 (=1024-elem) tile
  const int n = p >> 1;          // block index, constant per thread
  const int h = p & 1;           // which half of the block I own

  // U rows o = h*4+j, columns permuted: [0..3]=own half, [4..7]=partner half.
  float u[4][8], v[4][8];
  #pragma unroll
  for (int j = 0; j < 4; ++j) {
    const float* urow = Urg + n * 64 + (h * 4 + j) * 8;
    const float* vrow = Uig + n * 64 + (h * 4 + j) * 8;
    float4 uo = *(const float4*)(urow + h * 4);
    float4 up = *(const float4*)(urow + (h ^ 1) * 4);
    float4 vo = *(const float4*)(vrow + h * 4);
    float4 vp = *(const float4*)(vrow + (h ^ 1) * 4);
    u[j][0] = uo.x; u[j][1] = uo.y; u[j][2] = uo.z; u[j][3] = uo.w;
    u[j][4] = up.x; u[j][5] = up.y; u[j][6] = up.z; u[j][7] = up.w;
    v[j][0] = vo.x; v[j][1] = vo.y; v[j][2] = vo.z; v[j][3] = vo.w;
    v[j][4] = vp.x; v[j][5] = vp.y; v[j][6] = vp.z; v[j][7] = vp.w;
  }
  // Pin U in registers (R1 failure mode: compiler sinks U loads into loop).
  #pragma unroll
  for (int j = 0; j < 4; ++j)
    #pragma unroll
    for (int c = 0; c < 8; ++c)
      asm volatile("" : "+v"(u[j][c]), "+v"(v[j][c]));

  const float4* pxr = (const float4*)xr;
  const float4* pxi = (const float4*)xi;
  floatx4* qor = (floatx4*)out;
  floatx4* qoi = (floatx4*)(out + PLANE);

  #pragma unroll 2
  for (int k = 0; k < NITER; ++k) {
    const int idx = k * THREADS + G;     // dense float4 index; partner = idx^1
    float4 a  = pxr[idx];                // own half, xr
    float4 b  = pxi[idx];                // own half, xi
    float4 ap = pxr[idx ^ 1];            // partner half, xr (same L1 lines)
    float4 bp = pxi[idx ^ 1];            // partner half, xi

    float oxr[4] = {a.x, a.y, a.z, a.w};
    float oxi[4] = {b.x, b.y, b.z, b.w};
    float wxr[4] = {ap.x, ap.y, ap.z, ap.w};
    float wxi[4] = {bp.x, bp.y, bp.z, bp.w};

    float rr[4], ii[4];
    // Phase 1: own-half contributions only (needs a,b -> vmcnt(2)).
    #pragma unroll
    for (int j = 0; j < 4; ++j) {
      float r0 = u[j][0] * oxr[0];
      float i0 = u[j][0] * oxi[0];
      #pragma unroll
      for (int c = 1; c < 4; ++c) {
        r0 = fmaf(u[j][c], oxr[c], r0);
        i0 = fmaf(u[j][c], oxi[c], i0);
      }
      #pragma unroll
      for (int c = 0; c < 4; ++c) {
        r0 = fmaf(-v[j][c], oxi[c], r0);
        i0 = fmaf(v[j][c], oxr[c], i0);
      }
      rr[j] = r0; ii[j] = i0;
    }
    // Phase 2: partner-half contributions (needs ap,bp -> vmcnt(0)).
    floatx4 sr, si;
    #pragma unroll
    for (int j = 0; j < 4; ++j) {
      float r0 = rr[j], i0 = ii[j];
      #pragma unroll
      for (int c = 0; c < 4; ++c) {
        r0 = fmaf(u[j][4 + c], wxr[c], r0);
        i0 = fmaf(u[j][4 + c], wxi[c], i0);
      }
      #pragma unroll
      for (int c = 0; c < 4; ++c) {
        r0 = fmaf(-v[j][4 + c], wxi[c], r0);
        i0 = fmaf(v[j][4 + c], wxr[c], i0);
      }
      sr[j] = r0; si[j] = i0;
    }

    // Volatile but NO memory clobber: stays ordered vs other volatile asms,
    // while next iteration's x loads are free to hoist above.
    asm volatile("global_store_dwordx4 %0, %1, off sc0 sc1 nt"
                 :: "v"(qor + idx), "v"(sr));
    asm volatile("global_store_dwordx4 %0, %1, off sc0 sc1 nt"
                 :: "v"(qoi + idx), "v"(si));
  }

  // Drain asm stores before wave exit (volatile: ordered after all stores).
  asm volatile("s_waitcnt vmcnt(0)" ::: "memory");
}

extern "C" void kernel_launch(void* const* d_in, const int* in_sizes, int n_in,
                              void* d_out, int out_size, void* d_ws, size_t ws_size,
                              hipStream_t stream) {
  const float* xr = (const float*)d_in[0];
  const float* xi = (const float*)d_in[1];
  const float* Ar = (const float*)d_in[2];
  const float* Ai = (const float*)d_in[3];
  float* out = (float*)d_out;

  float* Ur = (float*)d_ws;              // 128*64 floats = 32 KB
  float* Ui = Ur + NBLK * 64;            // next 32 KB

  cayley_kernel<<<32, 64, 0, stream>>>(Ar, Ai, Ur, Ui);
  apply_kernel<<<APPLY_WGS, 256, 0, stream>>>(xr, xi, Ur, Ui, out);
}